// Round 8
// baseline (312.437 us; speedup 1.0000x reference)
//
#include <hip/hip_runtime.h>

// AlphaCompositionShader: B=4,H=512,W=512,K=8.  P = B*H*W = 1048576 pixels.
// R5: R4's DPP compute (8 lanes/pixel, one lane per fragment, no LDS/barriers)
// made PERSISTENT: 2048 blocks grid-stride, each thread handles 16 fragments
// with a 2-deep register software pipeline (issue next iteration's 3 loads
// before consuming current data). Keeps ~6 loads in flight per wave
// continuously and removes one-shot wave launch/retire bubbles -> MLP fix for
// the 2.6 TB/s plateau (latency-bound: VALU 30%, occ 70%, nothing saturated).
// Width-8 scans/reductions via DPP (VALU pipe); labels nibble-packed; only 4
// ds_bpermute per fragment (human gather). All stores nontemporal.
// Output layout identical to prior rounds:
//   [0,4P) image | [4P,5P) depth | [5P,6P) label | [6P,38P) human

#define BKG_DEPTH 100.0f
#define KD 8

typedef float f32x4 __attribute__((ext_vector_type(4)));

#define QP_XOR1 0xB1              // quad_perm [1,0,3,2]
#define QP_XOR2 0x4E              // quad_perm [2,3,0,1]
#define ROW_SHL(n) (0x100 | (n))  // dst lane r <- src lane r+n (within 16-row)
#define ROW_SHR(n) (0x110 | (n))  // dst lane r <- src lane r-n (within 16-row)

template <int CTRL>
__device__ __forceinline__ float dppf(float x) {
    return __int_as_float(__builtin_amdgcn_update_dpp(
        0, __float_as_int(x), CTRL, 0xF, 0xF, true));
}
template <int CTRL>
__device__ __forceinline__ int dppi(int x) {
    return __builtin_amdgcn_update_dpp(0, x, CTRL, 0xF, 0xF, true);
}

__global__ __launch_bounds__(256) void alpha_comp_pipe(
    const float4* __restrict__ pc,   // P*8 rgba fragments
    const float*  __restrict__ zb,   // P*8 z
    const int*    __restrict__ lb,   // P*8 labels (0..7)
    const float*  __restrict__ bg,   // 3 floats
    float* __restrict__ out,
    int P)
{
    const int stride = gridDim.x * blockDim.x;
    const int total  = P * KD;
    int t = blockIdx.x * blockDim.x + threadIdx.x;   // fragment index
    if (t >= total) return;

    const int kk   = t & 7;                          // loop-invariant (stride%8==0)
    const int lane = threadIdx.x & 63;
    const float bg0 = bg[0], bg1 = bg[1], bg2 = bg[2];

    // ---- pipeline prologue: first fragment's loads
    float4 c   = pc[t];
    float  z   = zb[t];
    int    lbl = lb[t];

    while (true) {
        // ---- prefetch next iteration (issues before current data is consumed)
        const int  tn    = t + stride;
        const bool more  = tn < total;
        const int  tload = more ? tn : t;            // clamp: harmless re-read
        const float4 cn   = pc[tload];
        const float  zn   = zb[tload];
        const int    lbln = lb[tload];

        // ================= compute current fragment t =================
        const int   pix   = t >> 3;
        const float alpha = c.w;
        const bool  valid = !(z < 0.0f);

        // inclusive prefix product of (1-a) via DPP scan (3 steps)
        float incl = 1.0f - alpha;
        { const float u = dppf<ROW_SHR(1)>(incl); incl = (kk >= 1) ? incl * u : incl; }
        { const float u = dppf<ROW_SHR(2)>(incl); incl = (kk >= 2) ? incl * u : incl; }
        { const float u = dppf<ROW_SHR(4)>(incl); incl = (kk >= 4) ? incl * u : incl; }
        float pre = dppf<ROW_SHR(1)>(incl); pre = (kk == 0) ? 1.0f : pre;  // exclusive
        const float T = dppf<ROW_SHL(7)>(incl);   // full product, valid in lane kk==0
        const float w = alpha * pre;

        // rgb weighted sums + max alpha (totals valid in kk<4 after combine)
        float sr = c.x * w, sg = c.y * w, sb = c.z * w, am = alpha;
        sr += dppf<QP_XOR1>(sr); sg += dppf<QP_XOR1>(sg); sb += dppf<QP_XOR1>(sb);
        am = fmaxf(am, dppf<QP_XOR1>(am));
        sr += dppf<QP_XOR2>(sr); sg += dppf<QP_XOR2>(sg); sb += dppf<QP_XOR2>(sb);
        am = fmaxf(am, dppf<QP_XOR2>(am));
        sr += dppf<ROW_SHL(4)>(sr); sg += dppf<ROW_SHL(4)>(sg); sb += dppf<ROW_SHL(4)>(sb);
        am = fmaxf(am, dppf<ROW_SHL(4)>(am));

        // depth: layers with z>0 participate, others transparent
        const float a2 = (z > 0.0f) ? alpha : 0.0f;
        float incl2 = 1.0f - a2;
        { const float u = dppf<ROW_SHR(1)>(incl2); incl2 = (kk >= 1) ? incl2 * u : incl2; }
        { const float u = dppf<ROW_SHR(2)>(incl2); incl2 = (kk >= 2) ? incl2 * u : incl2; }
        { const float u = dppf<ROW_SHR(4)>(incl2); incl2 = (kk >= 4) ? incl2 * u : incl2; }
        float pre2 = dppf<ROW_SHR(1)>(incl2); pre2 = (kk == 0) ? 1.0f : pre2;
        const float T2 = dppf<ROW_SHL(6)>(incl2); // full product, valid in lane kk==1
        float sd = z * (a2 * pre2);               // 0 when a2==0
        sd += dppf<QP_XOR1>(sd);
        sd += dppf<QP_XOR2>(sd);
        sd += dppf<ROW_SHL(4)>(sd);
        const float outD = fmaf(BKG_DEPTH, T2, sd);

        // pack all 8 labels as nibbles into one word (every lane gets full word)
        int pw = (valid ? lbl : 0xF) << (4 * kk);
        pw |= dppi<QP_XOR1>(pw);
        pw |= dppi<QP_XOR2>(pw);
        {
            const int lo = dppi<ROW_SHL(4)>(pw);  // other quad, valid for kk<4
            const int hi = dppi<ROW_SHR(4)>(pw);  // other quad, valid for kk>=4
            pw |= (kk & 4) ? hi : lo;
        }

        // composite label: min k with (valid && alpha>0.5), else -1
        const unsigned long long bal = __ballot(valid && (alpha > 0.5f));
        const unsigned grpByte = (unsigned)((bal >> (lane & ~7)) & 0xFFull);
        const int jlab = grpByte ? (__ffs(grpByte) - 1) : 0;
        const float labv = grpByte ? (float)((pw >> (4 * jlab)) & 0xF) : -1.0f;

        // human image for label n = kk: front-most fragment with nibble==kk
        int jm = 8;                                // sentinel: no hit
        #pragma unroll
        for (int j = 7; j >= 0; --j)
            jm = (((pw >> (4 * j)) & 0xF) == kk) ? j : jm;
        const bool hit = (jm < 8);
        const int src = hit ? jm : 0;
        float gx = __shfl(c.x, src, 8);            // the only 4 ds_bpermute ops
        float gy = __shfl(c.y, src, 8);
        float gz = __shfl(c.z, src, 8);
        float gw = __shfl(c.w, src, 8);
        gx = hit ? gx : 0.0f;  gy = hit ? gy : 0.0f;
        gz = hit ? gz : 0.0f;  gw = hit ? gw : 0.0f;
        const float ia = 1.0f - gw;
        const f32x4 hv = { fmaf(gx, gw, bg0 * ia),
                           fmaf(gy, gw, bg1 * ia),
                           fmaf(gz, gw, bg2 * ia),
                           gw };

        // stores (all streams lane-consecutive or dense; nontemporal)
        __builtin_nontemporal_store(hv, &((f32x4*)(out + (size_t)6 * P))[t]);
        if (kk == 0) {
            const f32x4 img = { fmaf(bg0, T, sr), fmaf(bg1, T, sg), fmaf(bg2, T, sb), am };
            __builtin_nontemporal_store(img, &((f32x4*)out)[pix]);
        }
        if (kk == 1) __builtin_nontemporal_store(outD, &out[(size_t)4 * P + pix]);
        if (kk == 2) __builtin_nontemporal_store(labv, &out[(size_t)5 * P + pix]);
        // ==============================================================

        if (!more) break;
        t = tn; c = cn; z = zn; lbl = lbln;
    }
}

extern "C" void kernel_launch(void* const* d_in, const int* in_sizes, int n_in,
                              void* d_out, int out_size, void* d_ws, size_t ws_size,
                              hipStream_t stream) {
    const float4* pc = (const float4*)d_in[0];   // pixel_colors (B,H,W,K,4) f32
    const float*  zb = (const float*)d_in[1];    // zbuf (B,H,W,K) f32
    const int*    lb = (const int*)d_in[2];      // pixel_labels (B,H,W,K) i32
    const float*  bg = (const float*)d_in[3];    // background_color (3,) f32
    float* out = (float*)d_out;

    const int P = in_sizes[1] / KD;              // B*H*W = 1048576
    const int total = P * KD;                    // one lane per fragment
    const int block = 256;
    int grid = (total + block - 1) / block;
    if (grid > 2048) grid = 2048;                // persistent: 8 blocks/CU, 16 iters
    alpha_comp_pipe<<<grid, block, 0, stream>>>(pc, zb, lb, bg, out, P);
}

// Round 9
// 312.299 us; speedup vs baseline: 1.0004x; 1.0004x over previous
//
#include <hip/hip_runtime.h>

// AlphaCompositionShader: B=4,H=512,W=512,K=8.  P = B*H*W = 1048576 pixels.
// R6: R4's DPP one-shot structure (8 lanes/pixel, one lane per fragment, no
// LDS, no barriers, no loops) with 4x FATTER THREADS: each thread handles 4
// fragments at stride total/4 (all streams stay lane-consecutive). All 12
// loads issue in one up-front burst grouped per fragment-set, so compute of
// set j waits at vmcnt(9-3j): a 4-stage pipeline in straight-line code.
// Raises per-wave in-flight bytes 4x and amortizes per-wave latency/launch
// cost 4x WITHOUT collapsing TLP (32K waves) or adding loop overhead (R5's
// mistake: persistent loop cut TLP 16x and regressed 100->116us).
// Width-8 scans via DPP; labels nibble-packed; 4 ds_bpermute per fragment.
// All stores nontemporal. Output layout identical to prior rounds:
//   [0,4P) image | [4P,5P) depth | [5P,6P) label | [6P,38P) human

#define BKG_DEPTH 100.0f
#define KD 8
#define UNROLL 4

typedef float f32x4 __attribute__((ext_vector_type(4)));

#define QP_XOR1 0xB1              // quad_perm [1,0,3,2]
#define QP_XOR2 0x4E              // quad_perm [2,3,0,1]
#define ROW_SHL(n) (0x100 | (n))  // dst lane r <- src lane r+n (within 16-row)
#define ROW_SHR(n) (0x110 | (n))  // dst lane r <- src lane r-n (within 16-row)

template <int CTRL>
__device__ __forceinline__ float dppf(float x) {
    return __int_as_float(__builtin_amdgcn_update_dpp(
        0, __float_as_int(x), CTRL, 0xF, 0xF, true));
}
template <int CTRL>
__device__ __forceinline__ int dppi(int x) {
    return __builtin_amdgcn_update_dpp(0, x, CTRL, 0xF, 0xF, true);
}

__global__ __launch_bounds__(256) void alpha_comp_fat(
    const float4* __restrict__ pc,   // P*8 rgba fragments
    const float*  __restrict__ zb,   // P*8 z
    const int*    __restrict__ lb,   // P*8 labels (0..7)
    const float*  __restrict__ bg,   // 3 floats
    float* __restrict__ out,
    int P)
{
    const int total = P * KD;
    const int S     = total / UNROLL;                // fragment-set stride
    const int t0    = blockIdx.x * blockDim.x + threadIdx.x;
    if (t0 >= S) return;                             // grid exact; safety only

    const int kk   = t0 & 7;                         // same for all 4 sets (S%8==0)
    const int lane = threadIdx.x & 63;
    const float bg0 = bg[0], bg1 = bg[1], bg2 = bg[2];

    // ---- load burst: 12 loads, grouped per set (set j completes at vmcnt(9-3j))
    float4 c[UNROLL]; float z[UNROLL]; int lbl[UNROLL];
    #pragma unroll
    for (int j = 0; j < UNROLL; ++j) {
        const int t = t0 + j * S;
        c[j]   = pc[t];
        z[j]   = zb[t];
        lbl[j] = lb[t];
    }

    // ---- 4 independent compute+store groups (compile-time indices only)
    #pragma unroll
    for (int j = 0; j < UNROLL; ++j) {
        const int   t     = t0 + j * S;
        const int   pix   = t >> 3;
        const float alpha = c[j].w;
        const bool  valid = !(z[j] < 0.0f);

        // inclusive prefix product of (1-a) via DPP scan (3 steps)
        float incl = 1.0f - alpha;
        { const float u = dppf<ROW_SHR(1)>(incl); incl = (kk >= 1) ? incl * u : incl; }
        { const float u = dppf<ROW_SHR(2)>(incl); incl = (kk >= 2) ? incl * u : incl; }
        { const float u = dppf<ROW_SHR(4)>(incl); incl = (kk >= 4) ? incl * u : incl; }
        float pre = dppf<ROW_SHR(1)>(incl); pre = (kk == 0) ? 1.0f : pre;  // exclusive
        const float T = dppf<ROW_SHL(7)>(incl);   // full product, valid in lane kk==0
        const float w = alpha * pre;

        // rgb weighted sums + max alpha (totals valid in kk<4 after combine)
        float sr = c[j].x * w, sg = c[j].y * w, sb = c[j].z * w, am = alpha;
        sr += dppf<QP_XOR1>(sr); sg += dppf<QP_XOR1>(sg); sb += dppf<QP_XOR1>(sb);
        am = fmaxf(am, dppf<QP_XOR1>(am));
        sr += dppf<QP_XOR2>(sr); sg += dppf<QP_XOR2>(sg); sb += dppf<QP_XOR2>(sb);
        am = fmaxf(am, dppf<QP_XOR2>(am));
        sr += dppf<ROW_SHL(4)>(sr); sg += dppf<ROW_SHL(4)>(sg); sb += dppf<ROW_SHL(4)>(sb);
        am = fmaxf(am, dppf<ROW_SHL(4)>(am));

        // depth: layers with z>0 participate, others transparent
        const float a2 = (z[j] > 0.0f) ? alpha : 0.0f;
        float incl2 = 1.0f - a2;
        { const float u = dppf<ROW_SHR(1)>(incl2); incl2 = (kk >= 1) ? incl2 * u : incl2; }
        { const float u = dppf<ROW_SHR(2)>(incl2); incl2 = (kk >= 2) ? incl2 * u : incl2; }
        { const float u = dppf<ROW_SHR(4)>(incl2); incl2 = (kk >= 4) ? incl2 * u : incl2; }
        float pre2 = dppf<ROW_SHR(1)>(incl2); pre2 = (kk == 0) ? 1.0f : pre2;
        const float T2 = dppf<ROW_SHL(6)>(incl2); // full product, valid in lane kk==1
        float sd = z[j] * (a2 * pre2);            // 0 when a2==0
        sd += dppf<QP_XOR1>(sd);
        sd += dppf<QP_XOR2>(sd);
        sd += dppf<ROW_SHL(4)>(sd);
        const float outD = fmaf(BKG_DEPTH, T2, sd);

        // pack all 8 labels as nibbles into one word (every lane gets full word)
        int pw = (valid ? lbl[j] : 0xF) << (4 * kk);
        pw |= dppi<QP_XOR1>(pw);
        pw |= dppi<QP_XOR2>(pw);
        {
            const int lo = dppi<ROW_SHL(4)>(pw);  // other quad, valid for kk<4
            const int hi = dppi<ROW_SHR(4)>(pw);  // other quad, valid for kk>=4
            pw |= (kk & 4) ? hi : lo;
        }

        // composite label: min k with (valid && alpha>0.5), else -1
        const unsigned long long bal = __ballot(valid && (alpha > 0.5f));
        const unsigned grpByte = (unsigned)((bal >> (lane & ~7)) & 0xFFull);
        const int jlab = grpByte ? (__ffs(grpByte) - 1) : 0;
        const float labv = grpByte ? (float)((pw >> (4 * jlab)) & 0xF) : -1.0f;

        // human image for label n = kk: front-most fragment with nibble==kk
        int jm = 8;                                // sentinel: no hit
        #pragma unroll
        for (int q = 7; q >= 0; --q)
            jm = (((pw >> (4 * q)) & 0xF) == kk) ? q : jm;
        const bool hit = (jm < 8);
        const int src = hit ? jm : 0;
        float gx = __shfl(c[j].x, src, 8);         // the only 4 ds_bpermute ops
        float gy = __shfl(c[j].y, src, 8);
        float gz = __shfl(c[j].z, src, 8);
        float gw = __shfl(c[j].w, src, 8);
        gx = hit ? gx : 0.0f;  gy = hit ? gy : 0.0f;
        gz = hit ? gz : 0.0f;  gw = hit ? gw : 0.0f;
        const float ia = 1.0f - gw;
        const f32x4 hv = { fmaf(gx, gw, bg0 * ia),
                           fmaf(gy, gw, bg1 * ia),
                           fmaf(gz, gw, bg2 * ia),
                           gw };

        // stores (all streams lane-consecutive or dense; nontemporal)
        __builtin_nontemporal_store(hv, &((f32x4*)(out + (size_t)6 * P))[t]);
        if (kk == 0) {
            const f32x4 img = { fmaf(bg0, T, sr), fmaf(bg1, T, sg), fmaf(bg2, T, sb), am };
            __builtin_nontemporal_store(img, &((f32x4*)out)[pix]);
        }
        if (kk == 1) __builtin_nontemporal_store(outD, &out[(size_t)4 * P + pix]);
        if (kk == 2) __builtin_nontemporal_store(labv, &out[(size_t)5 * P + pix]);
    }
}

extern "C" void kernel_launch(void* const* d_in, const int* in_sizes, int n_in,
                              void* d_out, int out_size, void* d_ws, size_t ws_size,
                              hipStream_t stream) {
    const float4* pc = (const float4*)d_in[0];   // pixel_colors (B,H,W,K,4) f32
    const float*  zb = (const float*)d_in[1];    // zbuf (B,H,W,K) f32
    const int*    lb = (const int*)d_in[2];      // pixel_labels (B,H,W,K) i32
    const float*  bg = (const float*)d_in[3];    // background_color (3,) f32
    float* out = (float*)d_out;

    const int P = in_sizes[1] / KD;              // B*H*W = 1048576
    const int total = P * KD;                    // one lane per fragment
    const int S = total / UNROLL;                // 2097152 threads
    const int block = 256;
    const int grid = (S + block - 1) / block;    // 8192 blocks
    alpha_comp_fat<<<grid, block, 0, stream>>>(pc, zb, lb, bg, out, P);
}

// Round 11
// 292.011 us; speedup vs baseline: 1.0699x; 1.0695x over previous
//
#include <hip/hip_runtime.h>

// AlphaCompositionShader: B=4,H=512,W=512,K=8.  P = B*H*W = 1048576 pixels.
// R7 (resubmit; GPU-acquisition timeout, never measured): exact A/B vs R4
// (100us best): ONLY change is nontemporal stores -> PLAIN stores.
// R1(~96us, plain stores + 38 bpermutes) vs R4(100us, nt stores + DPP)
// differ by two variables; DPP is clearly cheaper than bpermute, so nt
// stores are the suspected ~10% regression source (no-allocate defeats
// L2/L3 write coalescing of the partial-line predicated stores and
// evict-first weakens L3 write buffering).
// Everything else identical to R4: 8 lanes/pixel, one lane per fragment,
// no LDS, no barriers, one-shot threads, width-8 scans via DPP, labels
// nibble-packed, 4 ds_bpermute per fragment (human gather).
// Output layout identical to prior rounds:
//   [0,4P) image | [4P,5P) depth | [5P,6P) label | [6P,38P) human

#define BKG_DEPTH 100.0f
#define KD 8

typedef float f32x4 __attribute__((ext_vector_type(4)));

#define QP_XOR1 0xB1              // quad_perm [1,0,3,2]
#define QP_XOR2 0x4E              // quad_perm [2,3,0,1]
#define ROW_SHL(n) (0x100 | (n))  // dst lane r <- src lane r+n (within 16-row)
#define ROW_SHR(n) (0x110 | (n))  // dst lane r <- src lane r-n (within 16-row)

template <int CTRL>
__device__ __forceinline__ float dppf(float x) {
    return __int_as_float(__builtin_amdgcn_update_dpp(
        0, __float_as_int(x), CTRL, 0xF, 0xF, true));
}
template <int CTRL>
__device__ __forceinline__ int dppi(int x) {
    return __builtin_amdgcn_update_dpp(0, x, CTRL, 0xF, 0xF, true);
}

__global__ __launch_bounds__(256) void alpha_comp_dpp2(
    const float4* __restrict__ pc,   // P*8 rgba fragments
    const float*  __restrict__ zb,   // P*8 z
    const int*    __restrict__ lb,   // P*8 labels (0..7)
    const float*  __restrict__ bg,   // 3 floats
    float* __restrict__ out,
    int P)
{
    const int tid = blockIdx.x * blockDim.x + threadIdx.x;  // global fragment idx
    const int pix = tid >> 3;
    const int kk  = tid & 7;                                // fragment k == human label n
    if (pix >= P) return;                                   // grid is exact; safety only

    const float bg0 = bg[0], bg1 = bg[1], bg2 = bg[2];

    // ---- fully coalesced loads (lane-consecutive, 24 B/lane)
    const float4 c     = pc[tid];
    const float  z     = zb[tid];
    const int    lbl   = lb[tid];
    const float  alpha = c.w;
    const bool   valid = !(z < 0.0f);

    // ---- inclusive prefix product of (1-a) via DPP scan (3 steps)
    float incl = 1.0f - alpha;
    { const float u = dppf<ROW_SHR(1)>(incl); incl = (kk >= 1) ? incl * u : incl; }
    { const float u = dppf<ROW_SHR(2)>(incl); incl = (kk >= 2) ? incl * u : incl; }
    { const float u = dppf<ROW_SHR(4)>(incl); incl = (kk >= 4) ? incl * u : incl; }
    float pre = dppf<ROW_SHR(1)>(incl); pre = (kk == 0) ? 1.0f : pre;  // exclusive
    const float T = dppf<ROW_SHL(7)>(incl);   // full product, valid in lane kk==0
    const float w = alpha * pre;

    // ---- rgb weighted sums + max alpha (totals valid in kk<4 after combine)
    float sr = c.x * w, sg = c.y * w, sb = c.z * w, am = alpha;
    sr += dppf<QP_XOR1>(sr); sg += dppf<QP_XOR1>(sg); sb += dppf<QP_XOR1>(sb);
    am = fmaxf(am, dppf<QP_XOR1>(am));
    sr += dppf<QP_XOR2>(sr); sg += dppf<QP_XOR2>(sg); sb += dppf<QP_XOR2>(sb);
    am = fmaxf(am, dppf<QP_XOR2>(am));
    sr += dppf<ROW_SHL(4)>(sr); sg += dppf<ROW_SHL(4)>(sg); sb += dppf<ROW_SHL(4)>(sb);
    am = fmaxf(am, dppf<ROW_SHL(4)>(am));    // fmax(x,0) harmless in unused lanes

    // ---- depth: layers with z>0 participate, others transparent
    const float a2 = (z > 0.0f) ? alpha : 0.0f;
    float incl2 = 1.0f - a2;
    { const float u = dppf<ROW_SHR(1)>(incl2); incl2 = (kk >= 1) ? incl2 * u : incl2; }
    { const float u = dppf<ROW_SHR(2)>(incl2); incl2 = (kk >= 2) ? incl2 * u : incl2; }
    { const float u = dppf<ROW_SHR(4)>(incl2); incl2 = (kk >= 4) ? incl2 * u : incl2; }
    float pre2 = dppf<ROW_SHR(1)>(incl2); pre2 = (kk == 0) ? 1.0f : pre2;
    const float T2 = dppf<ROW_SHL(6)>(incl2); // full product, valid in lane kk==1
    float sd = z * (a2 * pre2);               // 0 when a2==0
    sd += dppf<QP_XOR1>(sd);
    sd += dppf<QP_XOR2>(sd);
    sd += dppf<ROW_SHL(4)>(sd);               // total valid in kk<4
    const float outD = fmaf(BKG_DEPTH, T2, sd);

    // ---- pack all 8 labels as nibbles into one word (every lane gets full word)
    int pw = (valid ? lbl : 0xF) << (4 * kk);
    pw |= dppi<QP_XOR1>(pw);
    pw |= dppi<QP_XOR2>(pw);
    {
        const int lo = dppi<ROW_SHL(4)>(pw);  // other quad, valid for kk<4
        const int hi = dppi<ROW_SHR(4)>(pw);  // other quad, valid for kk>=4
        pw |= (kk & 4) ? hi : lo;
    }

    // ---- composite label: min k with (valid && alpha>0.5), else -1
    const unsigned long long bal = __ballot(valid && (alpha > 0.5f));
    const int lane = threadIdx.x & 63;
    const unsigned grpByte = (unsigned)((bal >> (lane & ~7)) & 0xFFull);
    const int jlab = grpByte ? (__ffs(grpByte) - 1) : 0;
    const float labv = grpByte ? (float)((pw >> (4 * jlab)) & 0xF) : -1.0f;

    // ---- human image for label n = kk: front-most fragment with nibble==kk
    int jm = 8;                                // sentinel: no hit
    #pragma unroll
    for (int j = 7; j >= 0; --j)
        jm = (((pw >> (4 * j)) & 0xF) == kk) ? j : jm;
    const bool hit = (jm < 8);
    const int src = hit ? jm : 0;
    float gx = __shfl(c.x, src, 8);            // the only 4 ds_bpermute ops
    float gy = __shfl(c.y, src, 8);
    float gz = __shfl(c.z, src, 8);
    float gw = __shfl(c.w, src, 8);
    gx = hit ? gx : 0.0f;  gy = hit ? gy : 0.0f;
    gz = hit ? gz : 0.0f;  gw = hit ? gw : 0.0f;
    const float ia = 1.0f - gw;
    const f32x4 hv = { fmaf(gx, gw, bg0 * ia),
                       fmaf(gy, gw, bg1 * ia),
                       fmaf(gz, gw, bg2 * ia),
                       gw };

    // ---- stores: PLAIN (the only change vs R4)
    ((f32x4*)(out + (size_t)6 * P))[tid] = hv;
    if (kk == 0) {
        const f32x4 img = { fmaf(bg0, T, sr), fmaf(bg1, T, sg), fmaf(bg2, T, sb), am };
        ((f32x4*)out)[pix] = img;
    }
    if (kk == 1) out[(size_t)4 * P + pix] = outD;
    if (kk == 2) out[(size_t)5 * P + pix] = labv;
}

extern "C" void kernel_launch(void* const* d_in, const int* in_sizes, int n_in,
                              void* d_out, int out_size, void* d_ws, size_t ws_size,
                              hipStream_t stream) {
    const float4* pc = (const float4*)d_in[0];   // pixel_colors (B,H,W,K,4) f32
    const float*  zb = (const float*)d_in[1];    // zbuf (B,H,W,K) f32
    const int*    lb = (const int*)d_in[2];      // pixel_labels (B,H,W,K) i32
    const float*  bg = (const float*)d_in[3];    // background_color (3,) f32
    float* out = (float*)d_out;

    const int P = in_sizes[1] / KD;              // B*H*W = 1048576
    const int total = P * KD;                    // one thread per fragment
    const int block = 256;
    const int grid = (total + block - 1) / block;
    alpha_comp_dpp2<<<grid, block, 0, stream>>>(pc, zb, lb, bg, out, P);
}